// Round 7
// baseline (405.265 us; speedup 1.0000x reference)
//
#include <hip/hip_runtime.h>
#include <hip/hip_bf16.h>

#define DM   1024
#define DFF  4096
#define NB   4
#define SS   2048
#define NH   16
#define DK   64
#define MROWS (NB*SS)   // 8192

typedef __attribute__((ext_vector_type(8))) short bfx8;
typedef __attribute__((ext_vector_type(4))) float fx4;
typedef unsigned int u32;
typedef unsigned short u16;

static __device__ __forceinline__ u16 f2bf(float f) {
  union { __hip_bfloat16 h; u16 u; } cv;
  cv.h = __float2bfloat16(f);
  return cv.u;
}
static __device__ __forceinline__ u32 pk2bf(float a, float b) {
  return (u32)f2bf(a) | ((u32)f2bf(b) << 16);
}

static __device__ __forceinline__ void async16(void* lds, const void* g) {
  typedef const __attribute__((address_space(1))) unsigned int* gp_t;
  typedef __attribute__((address_space(3))) unsigned int* lp_t;
  __builtin_amdgcn_global_load_lds((gp_t)g, (lp_t)lds, 16, 0, 0);
}

// ---------------- weight transpose + f32->bf16 cast: out[n][k] = in[k][n] ----
__global__ __launch_bounds__(256) void k_transpose(const float* __restrict__ in,
                                                   u16* __restrict__ out,
                                                   int K, int N) {
  __shared__ float t[32][33];
  const int n0 = blockIdx.x * 32, k0 = blockIdx.y * 32;
  const int tx = threadIdx.x & 31, ty = threadIdx.x >> 5;  // 32 x 8
#pragma unroll
  for (int j = 0; j < 4; j++)
    t[ty + j * 8][tx] = in[(size_t)(k0 + ty + j * 8) * N + n0 + tx];
  __syncthreads();
#pragma unroll
  for (int j = 0; j < 4; j++)
    out[(size_t)(n0 + ty + j * 8) * K + k0 + tx] = f2bf(t[tx][ty + j * 8]);
}

// ---------------- layernorm: f32 in -> bf16 out, one wave per row ----------
__global__ __launch_bounds__(256) void k_layernorm(const float* __restrict__ x,
                                                   const float* __restrict__ g,
                                                   const float* __restrict__ b,
                                                   u16* __restrict__ out) {
  const int row  = blockIdx.x * 4 + (threadIdx.x >> 6);
  const int lane = threadIdx.x & 63;
  const float* xr = x + (size_t)row * DM;
  float4 vb[4];
  float s = 0.f, s2 = 0.f;
#pragma unroll
  for (int j = 0; j < 4; j++) {
    float4 v = *(const float4*)(xr + j * 256 + lane * 4);
    vb[j] = v;
    s  += v.x + v.y + v.z + v.w;
    s2 += v.x * v.x + v.y * v.y + v.z * v.z + v.w * v.w;
  }
#pragma unroll
  for (int off = 1; off < 64; off <<= 1) {
    s  += __shfl_xor(s,  off);
    s2 += __shfl_xor(s2, off);
  }
  const float mu   = s * (1.f / DM);
  const float var  = s2 * (1.f / DM) - mu * mu;
  const float rstd = rsqrtf(var + 1e-5f);
  u16* orow = out + (size_t)row * DM;
#pragma unroll
  for (int j = 0; j < 4; j++) {
    const int col = j * 256 + lane * 4;
    uint2 o;
    o.x = pk2bf((vb[j].x - mu) * rstd * g[col + 0] + b[col + 0],
                (vb[j].y - mu) * rstd * g[col + 1] + b[col + 1]);
    o.y = pk2bf((vb[j].z - mu) * rstd * g[col + 2] + b[col + 2],
                (vb[j].w - mu) * rstd * g[col + 3] + b[col + 3]);
    *(uint2*)(orow + col) = o;
  }
}

// ---------------- GEMM: C[M,N] = A[M,K](bf16) @ BT[N,K](bf16)^T + bias -----
// BM=256, 8 waves (512 thr). NWR waves in M (2 or 4); BN = (8/NWR)*64.
// BK=32, 64B LDS rows (bank-uniform, no swizzle), QUAD-buffered, depth-3
// prefetch, ONE barrier per K-step, counted vmcnt (never 0 mid-loop).
// EPI: 1 = f32 out (+res), 2 = bf16 gelu out, 4 = fused QKV
template <int EPI, int NWR>
__global__ __launch_bounds__(512, 2) void k_gemm_bt(const u16* __restrict__ A,
                                                    const u16* __restrict__ BT,
                                                    const float* __restrict__ bias0,
                                                    const float* __restrict__ bias1,
                                                    const float* __restrict__ bias2,
                                                    const float* __restrict__ res,
                                                    void* __restrict__ outp,
                                                    int M, int N, int K) {
  constexpr int NWC    = 8 / NWR;
  constexpr int BN     = NWC * 64;          // 256 or 128
  constexpr int MFRAG  = 256 / NWR / 16;    // 8 or 4
  constexpr int ABYTES = 256 * 32 * 2;      // 16 KB per K-tile
  constexpr int BBYTES = BN * 32 * 2;       // 16 or 8 KB
  constexpr int LA     = ABYTES / (512 * 16);  // 2
  constexpr int LB     = BBYTES / (512 * 16);  // 2 or 1
  constexpr int L      = LA + LB;

  __shared__ char Al[4 * ABYTES];
  __shared__ char Bl[4 * BBYTES];

  const int tid = threadIdx.x, wave = tid >> 6, lane = tid & 63;
  // XCD-aware chunked swizzle (nwg % 8 == 0 for all our launches)
  const int nwg = gridDim.x * gridDim.y;
  const int bid = blockIdx.y * gridDim.x + blockIdx.x;
  const int swz = (bid & 7) * (nwg >> 3) + (bid >> 3);
  const int m0 = (swz / gridDim.x) * 256, n0 = (swz % gridDim.x) * BN;
  const int wr = wave / NWC, wc = wave % NWC;
  const int wm = wr * (256 / NWR), wn = wc * 64;
  const int la = lane & 15, lg = lane >> 4;

  fx4 acc[MFRAG][4];
#pragma unroll
  for (int i = 0; i < MFRAG; i++)
#pragma unroll
    for (int j = 0; j < 4; j++) acc[i][j] = fx4{0.f, 0.f, 0.f, 0.f};

  // staging: thread tid's 16B lands at LDS offset (tid + j*512)*16
  // -> LDS [row][slot]: row = off/64, slot8 = (off%64)/16
  const int arow = tid >> 2, aslot = (tid & 3) * 8;
  const u16* gA = A  + (size_t)(m0 + arow) * K + aslot;
  const u16* gB = BT + (size_t)(n0 + arow) * K + aslot;   // arow < BN guaranteed via j-loop bound

  auto stageg = [&](int buf, int kt) {
#pragma unroll
    for (int j = 0; j < LA; j++)
      async16(Al + buf * ABYTES + j * 8192 + wave * 1024, gA + (size_t)(j * 128) * K + kt);
#pragma unroll
    for (int j = 0; j < LB; j++)
      async16(Bl + buf * BBYTES + j * 8192 + wave * 1024, gB + (size_t)(j * 128) * K + kt);
  };

  const int nk = K >> 5;
  stageg(0, 0);
  stageg(1, 32);
  stageg(2, 64);

  for (int t = 0; t < nk; ++t) {
    const int rem = nk - 1 - t;
    if (rem >= 2)      { asm volatile("s_waitcnt vmcnt(%0)" :: "n"(2 * L) : "memory"); }
    else if (rem == 1) { asm volatile("s_waitcnt vmcnt(%0)" :: "n"(L)     : "memory"); }
    else               { asm volatile("s_waitcnt vmcnt(0)" ::: "memory"); }
    __builtin_amdgcn_s_barrier();
    asm volatile("" ::: "memory");

    const char* Ab = (const char*)Al + (t & 3) * ABYTES;
    const char* Bb = (const char*)Bl + (t & 3) * BBYTES;
    bfx8 av[MFRAG], bv[4];
#pragma unroll
    for (int mt = 0; mt < MFRAG; mt++)
      av[mt] = *(const bfx8*)(Ab + (wm + mt * 16 + la) * 64 + lg * 16);
#pragma unroll
    for (int nt = 0; nt < 4; nt++)
      bv[nt] = *(const bfx8*)(Bb + (wn + nt * 16 + la) * 64 + lg * 16);

    if (t + 3 < nk) stageg((t + 3) & 3, (t + 3) * 32);

    __builtin_amdgcn_s_setprio(1);
#pragma unroll
    for (int mt = 0; mt < MFRAG; mt++)
#pragma unroll
      for (int nt = 0; nt < 4; nt++)
        acc[mt][nt] = __builtin_amdgcn_mfma_f32_16x16x32_bf16(av[mt], bv[nt], acc[mt][nt], 0, 0, 0);
    __builtin_amdgcn_s_setprio(0);
    asm volatile("" ::: "memory");
  }

  if constexpr (EPI == 4) {
    const int reg = n0 >> 10;  // 0=Q, 1=K, 2=V (block-uniform)
    const float* bp = (reg == 0) ? bias0 : (reg == 1) ? bias1 : bias2;
#pragma unroll
    for (int nt = 0; nt < 4; nt++) {
      const int n  = n0 + wn + nt * 16 + la;
      const int nl = n & 1023;
      const float bs = bp[nl];
      if (reg < 2) {
        u16* base = (u16*)outp + (size_t)reg * (8u * 1024 * 1024);
#pragma unroll
        for (int mt = 0; mt < MFRAG; mt++)
#pragma unroll
          for (int vv = 0; vv < 4; vv++) {
            const int m = m0 + wm + mt * 16 + lg * 4 + vv;
            base[(size_t)m * 1024 + nl] = f2bf(acc[mt][nt][vv] + bs);
          }
      } else {
        const int hh = nl >> 6, d = nl & 63;
#pragma unroll
        for (int mt = 0; mt < MFRAG; mt++) {
          const int m = m0 + wm + mt * 16 + lg * 4;
          const int bb = m >> 11, s = m & 2047;
          u16* vp = (u16*)outp + 16u * 1024 * 1024 +
                    (((size_t)bb * NH + hh) * DK + d) * SS + s;
          uint2 o;
          o.x = pk2bf(acc[mt][nt][0] + bs, acc[mt][nt][1] + bs);
          o.y = pk2bf(acc[mt][nt][2] + bs, acc[mt][nt][3] + bs);
          *(uint2*)vp = o;
        }
      }
    }
  } else {
#pragma unroll
    for (int nt = 0; nt < 4; nt++) {
      const int n = n0 + wn + nt * 16 + la;
      const float bs = bias0[n];
#pragma unroll
      for (int mt = 0; mt < MFRAG; mt++) {
#pragma unroll
        for (int vv = 0; vv < 4; vv++) {
          const int m = m0 + wm + mt * 16 + lg * 4 + vv;
          const float val = acc[mt][nt][vv] + bs;
          const size_t idx = (size_t)m * N + n;
          if constexpr (EPI == 1) {
            ((float*)outp)[idx] = res[idx] + val;
          } else {
            const float gl = 0.5f * val * (1.f + erff(val * 0.70710678118f));
            ((u16*)outp)[idx] = f2bf(gl);
          }
        }
      }
    }
  }
}

// ---------------- causal flash attention, swapped-QK^T, split-KV ----------
// grid 1024 x 512 threads = 8 waves = 2 groups of 4. Per block: 128 q-rows.
// Group g processes KV chunks (2i+g)*64; each group has its own double-buffered
// K/V in LDS (64 KB total). End: merge the two online-softmax partials via LDS.
__global__ __launch_bounds__(512, 4) void k_attn(const u16* __restrict__ q,
                                                 const u16* __restrict__ k,
                                                 const u16* __restrict__ vt,
                                                 u16* __restrict__ att) {
  __shared__ char sm[65536];   // [group][ K 2x8KB | V 2x8KB ]; merge scratch aliases
  const int bid = blockIdx.x;
  const int bq = 15 - (bid >> 6);
  const int bh = bid & 63;
  const int b = bh >> 4, h = bh & 15;

  const int tid = threadIdx.x, wave = tid >> 6, lane = tid & 63;
  const int g = wave >> 2, wv4 = wave & 3;
  const int la = lane & 15, lg = lane >> 4;
  const int q0 = bq * 128;

  // Q fragments (B-operand): lane holds Q[q=qt*16+la][d = f*32 + lg*8 + j]
  bfx8 qf[2][2];
#pragma unroll
  for (int qt = 0; qt < 2; qt++) {
    const u16* qp = q + (size_t)(b * SS + q0 + wv4 * 32 + qt * 16 + la) * DM + h * DK + lg * 8;
#pragma unroll
    for (int f = 0; f < 2; f++) qf[qt][f] = *(const bfx8*)(qp + f * 32);
  }

  fx4 acc[2][4];
#pragma unroll
  for (int qt = 0; qt < 2; qt++)
#pragma unroll
    for (int dt = 0; dt < 4; dt++) acc[qt][dt] = fx4{0.f, 0.f, 0.f, 0.f};
  float mold[2] = {-10000.f, -10000.f};   // finite floor (log2 units)
  float lsum[2] = {0.f, 0.f};             // per-lane partial

  // staging (pre-swizzled global source, linear LDS dest)
  const int srow = lane >> 3;                   // 0..7
  const int sslot = (lane & 7) ^ srow;          // 16B slot
  const u16* kg0 = k  + (size_t)(b * SS + wv4 * 16 + srow) * DM + h * DK + sslot * 8;
  const u16* vg0 = vt + (size_t)((b * NH + h) * DK + wv4 * 16 + srow) * SS + sslot * 8;
  char* kbase = sm + g * 32768 + wv4 * 2048;            // + buf*8192
  char* vbase = sm + g * 32768 + 16384 + wv4 * 2048;

  const float c1 = 0.18033688f;  // 0.125 * log2(e)
  const int niter = bq + 1;      // chunks for this group: c = 2*i + g

  auto stage = [&](int buf, int i) {
    const int c0 = (2 * i + g) * 64;
#pragma unroll
    for (int j = 0; j < 2; j++)
      async16(kbase + buf * 8192 + j * 1024, kg0 + (size_t)(c0 + j * 8) * DM);
#pragma unroll
    for (int j = 0; j < 2; j++)
      async16(vbase + buf * 8192 + j * 1024, vg0 + (size_t)(j * 8) * SS + c0);
  };

  stage(0, 0);
  int cur = 0;
  const int sw = la & 7;

  for (int i = 0; i < niter; i++) {
    __syncthreads();                 // buf[cur] staged; prev reads done
    if (i + 1 < niter) stage(cur ^ 1, i + 1);
    const int c0 = (2 * i + g) * 64;
    const bool msk = (i == niter - 1);
    const char* Kb = sm + g * 32768 + cur * 8192;
    const char* Vb = sm + g * 32768 + 16384 + cur * 8192;

    // ---- S^T = K @ Q^T : lane holds S^T[kv=t*16+lg*4+r][q=qt*16+la] ----
    fx4 st[2][4];
    __builtin_amdgcn_s_setprio(1);
#pragma unroll
    for (int t = 0; t < 4; t++) {
      const char* kr = Kb + (size_t)(t * 16 + la) * 128;
      bfx8 kf0 = *(const bfx8*)(kr + ((0 + lg) ^ sw) * 16);
      bfx8 kf1 = *(const bfx8*)(kr + ((4 + lg) ^ sw) * 16);
#pragma unroll
      for (int qt = 0; qt < 2; qt++) {
        fx4 z = fx4{0.f, 0.f, 0.f, 0.f};
        z = __builtin_amdgcn_mfma_f32_16x16x32_bf16(kf0, qf[qt][0], z, 0, 0, 0);
        z = __builtin_amdgcn_mfma_f32_16x16x32_bf16(kf1, qf[qt][1], z, 0, 0, 0);
        st[qt][t] = z;
      }
    }
    __builtin_amdgcn_s_setprio(0);

    if (msk) {
#pragma unroll
      for (int qt = 0; qt < 2; qt++) {
        const int qir = q0 + wv4 * 32 + qt * 16 + la;
#pragma unroll
        for (int t = 0; t < 4; t++)
#pragma unroll
          for (int r = 0; r < 4; r++)
            if (c0 + t * 16 + lg * 4 + r > qir) st[qt][t][r] = -1e9f;
      }
    }

    // ---- softmax: shuffle-free deferred path; per-lane partial lsum ----
    float lmx[2];
#pragma unroll
    for (int qt = 0; qt < 2; qt++) {
      float mx = fmaxf(fmaxf(st[qt][0][0], st[qt][0][1]), fmaxf(st[qt][0][2], st[qt][0][3]));
#pragma unroll
      for (int t = 1; t < 4; t++)
        mx = fmaxf(mx, fmaxf(fmaxf(st[qt][t][0], st[qt][t][1]), fmaxf(st[qt][t][2], st[qt][t][3])));
      lmx[qt] = mx * c1;
    }
    const bool def = (lmx[0] <= mold[0] + 8.f) && (lmx[1] <= mold[1] + 8.f);
    if (!__all(def)) {
#pragma unroll
      for (int qt = 0; qt < 2; qt++) {
        float mx = lmx[qt];
        mx = fmaxf(mx, __shfl_xor(mx, 16));
        mx = fmaxf(mx, __shfl_xor(mx, 32));
        const float mnew  = fmaxf(mold[qt], mx);
        const float scale = exp2f(mold[qt] - mnew);
        mold[qt] = mnew;
        lsum[qt] *= scale;
#pragma unroll
        for (int dt = 0; dt < 4; dt++) {
          acc[qt][dt][0] *= scale; acc[qt][dt][1] *= scale;
          acc[qt][dt][2] *= scale; acc[qt][dt][3] *= scale;
        }
      }
    }
    u32 W[2][4][2];
#pragma unroll
    for (int qt = 0; qt < 2; qt++) {
      float ps = 0.f;
#pragma unroll
      for (int t = 0; t < 4; t++) {
        float p0 = exp2f(fmaf(st[qt][t][0], c1, -mold[qt]));
        float p1 = exp2f(fmaf(st[qt][t][1], c1, -mold[qt]));
        float p2 = exp2f(fmaf(st[qt][t][2], c1, -mold[qt]));
        float p3 = exp2f(fmaf(st[qt][t][3], c1, -mold[qt]));
        ps += (p0 + p1) + (p2 + p3);
        W[qt][t][0] = pk2bf(p0, p1);
        W[qt][t][1] = pk2bf(p2, p3);
      }
      lsum[qt] += ps;
    }

    // ---- PV: O^T += V^T @ P^T (P B-frag rebuilt in-register via shfl) ----
    const int sLo = la + ((lg & 1) << 5);
    const int sHi = sLo + 16;
    const bool tHi = (lg >> 1) & 1;
#pragma unroll
    for (int f = 0; f < 2; f++) {
      bfx8 pf[2];
#pragma unroll
      for (int qt = 0; qt < 2; qt++) {
        const u32 a0 = __shfl(W[qt][2 * f][0], sLo), b0 = __shfl(W[qt][2 * f + 1][0], sLo);
        const u32 a1 = __shfl(W[qt][2 * f][1], sLo), b1 = __shfl(W[qt][2 * f + 1][1], sLo);
        const u32 a2 = __shfl(W[qt][2 * f][0], sHi), b2 = __shfl(W[qt][2 * f + 1][0], sHi);
        const u32 a3 = __shfl(W[qt][2 * f][1], sHi), b3 = __shfl(W[qt][2 * f + 1][1], sHi);
        union { u32 u[4]; bfx8 v; } pu;
        pu.u[0] = tHi ? b0 : a0;
        pu.u[1] = tHi ? b1 : a1;
        pu.u[2] = tHi ? b2 : a2;
        pu.u[3] = tHi ? b3 : a3;
        pf[qt] = pu.v;
      }
      __builtin_amdgcn_s_setprio(1);
#pragma unroll
      for (int dt = 0; dt < 4; dt++) {
        const int row = dt * 16 + la;
        bfx8 vf = *(const bfx8*)(Vb + (size_t)row * 128 + (((f << 2) + lg) ^ sw) * 16);
        acc[0][dt] = __builtin_amdgcn_mfma_f32_16x16x32_bf16(vf, pf[0], acc[0][dt], 0, 0, 0);
        acc[1][dt] = __builtin_amdgcn_mfma_f32_16x16x32_bf16(vf, pf[1], acc[1][dt], 0, 0, 0);
      }
      __builtin_amdgcn_s_setprio(0);
    }
    cur ^= 1;
  }

  // ---- finalize per-group lsum (cross-lane, once) ----
#pragma unroll
  for (int qt = 0; qt < 2; qt++) {
    lsum[qt] += __shfl_xor(lsum[qt], 16);
    lsum[qt] += __shfl_xor(lsum[qt], 32);
  }

  // ---- merge group partials via LDS scratch (KV buffers dead) ----
  __syncthreads();
  const int gi = wv4 * 64 + lane;                  // 0..255 within group
  float* scr = (float*)sm + (size_t)gi * 36;       // 36 KB
  if (g == 1) {
#pragma unroll
    for (int qt = 0; qt < 2; qt++)
#pragma unroll
      for (int dt = 0; dt < 4; dt++)
#pragma unroll
        for (int j = 0; j < 4; j++) scr[qt * 16 + dt * 4 + j] = acc[qt][dt][j];
    scr[32] = mold[0]; scr[33] = mold[1];
    scr[34] = lsum[0]; scr[35] = lsum[1];
  }
  __syncthreads();
  if (g == 0) {
#pragma unroll
    for (int qt = 0; qt < 2; qt++) {
      const float mB = scr[32 + qt], lB = scr[34 + qt];
      const float mN = fmaxf(mold[qt], mB);
      const float sA = exp2f(mold[qt] - mN);
      const float sB = exp2f(mB - mN);
      const float inv = 1.f / (lsum[qt] * sA + lB * sB);
      u16* ob = att + (size_t)(b * SS + q0 + wv4 * 32 + qt * 16 + la) * DM + h * DK + lg * 4;
#pragma unroll
      for (int dt = 0; dt < 4; dt++) {
        float o0 = (acc[qt][dt][0] * sA + scr[qt * 16 + dt * 4 + 0] * sB) * inv;
        float o1 = (acc[qt][dt][1] * sA + scr[qt * 16 + dt * 4 + 1] * sB) * inv;
        float o2 = (acc[qt][dt][2] * sA + scr[qt * 16 + dt * 4 + 2] * sB) * inv;
        float o3 = (acc[qt][dt][3] * sA + scr[qt * 16 + dt * 4 + 3] * sB) * inv;
        uint2 o;
        o.x = pk2bf(o0, o1);
        o.y = pk2bf(o2, o3);
        *(uint2*)(ob + dt * 16) = o;
      }
    }
  }
}

// ---------------------------------------------------------------------------
extern "C" void kernel_launch(void* const* d_in, const int* in_sizes, int n_in,
                              void* d_out, int out_size, void* d_ws, size_t ws_size,
                              hipStream_t stream) {
  const float* x    = (const float*)d_in[0];
  const float* wq   = (const float*)d_in[1];
  const float* bq   = (const float*)d_in[2];
  const float* wk   = (const float*)d_in[3];
  const float* bk   = (const float*)d_in[4];
  const float* wv   = (const float*)d_in[5];
  const float* bv   = (const float*)d_in[6];
  const float* wo   = (const float*)d_in[7];
  const float* bo   = (const float*)d_in[8];
  const float* w1   = (const float*)d_in[9];
  const float* b1   = (const float*)d_in[10];
  const float* w2   = (const float*)d_in[11];
  const float* b2   = (const float*)d_in[12];
  const float* ln1g = (const float*)d_in[13];
  const float* ln1b = (const float*)d_in[14];
  const float* ln2g = (const float*)d_in[15];
  const float* ln2b = (const float*)d_in[16];
  float* out = (float*)d_out;

  char* w = (char*)d_ws;
  const size_t MB = 1024ull * 1024ull;
  u16*   wqkv = (u16*)(w + 0 * MB);   // [3072][1024] bf16 (Q,K,V stacked)
  u16*   wot  = (u16*)(w + 6 * MB);   // [1024][1024]
  u16*   w1t  = (u16*)(w + 8 * MB);   // [4096][1024]
  u16*   w2t  = (u16*)(w + 16 * MB);  // [1024][4096]
  float* x2   = (float*)(w + 24 * MB);// [8192][1024] f32
  u16*   hb   = (u16*)(w + 56 * MB);  // [8192][1024] (h, then h2)
  u16*   qb   = (u16*)(w + 72 * MB);  // [8192][1024]; K at +8M u16, V^T at +16M u16
  u16*   kb   = (u16*)(w + 88 * MB);
  u16*   vtb  = (u16*)(w + 104 * MB); // [4][16][64][2048] V^T per head
  u16*   atb  = (u16*)(w + 120 * MB); // [8192][1024]
  u16*   ffb  = (u16*)(w + 72 * MB);  // [8192][4096] overlays q/k/vt/att

  // 1) weight transposes (f32 -> bf16 W^T); QKV stacked into one [3072][1024]
  k_transpose<<<dim3(32, 32),  256, 0, stream>>>(wq, wqkv,               1024, 1024);
  k_transpose<<<dim3(32, 32),  256, 0, stream>>>(wk, wqkv + 1024 * 1024, 1024, 1024);
  k_transpose<<<dim3(32, 32),  256, 0, stream>>>(wv, wqkv + 2048 * 1024, 1024, 1024);
  k_transpose<<<dim3(32, 32),  256, 0, stream>>>(wo, wot, 1024, 1024);
  k_transpose<<<dim3(128, 32), 256, 0, stream>>>(w1, w1t, 1024, 4096);
  k_transpose<<<dim3(32, 128), 256, 0, stream>>>(w2, w2t, 4096, 1024);

  // 2) LN1: x -> h (bf16)
  k_layernorm<<<MROWS / 4, 256, 0, stream>>>(x, ln1g, ln1b, hb);

  // 3) fused QKV projection (Q,K row-major bf16; V per-head-transposed)
  //    BM=256, BN=128 -> grid 24x32 = 768 blocks (3/CU, even)
  k_gemm_bt<4, 4><<<dim3(24, 32), 512, 0, stream>>>(hb, wqkv, bq, bk, bv, nullptr, qb,
                                                    MROWS, 3 * DM, DM);

  // 4) causal flash attention (swapped QK^T, split-KV, 8 waves)
  k_attn<<<dim3(1024), 512, 0, stream>>>(qb, kb, vtb, atb);

  // 5) O projection + residual (f32 x2): BM=256, BN=128 -> 8x32 = 256 blocks
  k_gemm_bt<1, 4><<<dim3(8, 32), 512, 0, stream>>>(atb, wot, bo, nullptr, nullptr, x, x2,
                                                   MROWS, DM, DM);

  // 6) LN2: x2 -> h2 (bf16, reuse hb)
  k_layernorm<<<MROWS / 4, 256, 0, stream>>>(x2, ln2g, ln2b, hb);

  // 7) FF1 + GELU: BM=256, BN=256 -> 16x32 = 512 blocks (2/CU, even)
  k_gemm_bt<2, 2><<<dim3(16, 32), 512, 0, stream>>>(hb, w1t, b1, nullptr, nullptr, nullptr, ffb,
                                                    MROWS, DFF, DM);

  // 8) FF2 + residual -> d_out (f32): BM=256, BN=128 -> 8x32 = 256 blocks
  k_gemm_bt<1, 4><<<dim3(8, 32), 512, 0, stream>>>(ffb, w2t, b2, nullptr, nullptr, x2, out,
                                                   MROWS, DM, DFF);
}

// Round 8
// 401.209 us; speedup vs baseline: 1.0101x; 1.0101x over previous
//
#include <hip/hip_runtime.h>
#include <hip/hip_bf16.h>

#define DM   1024
#define DFF  4096
#define NB   4
#define SS   2048
#define NH   16
#define DK   64
#define MROWS (NB*SS)   // 8192

typedef __attribute__((ext_vector_type(8))) short bfx8;
typedef __attribute__((ext_vector_type(4))) float fx4;
typedef unsigned int u32;
typedef unsigned short u16;

static __device__ __forceinline__ u16 f2bf(float f) {
  union { __hip_bfloat16 h; u16 u; } cv;
  cv.h = __float2bfloat16(f);
  return cv.u;
}
static __device__ __forceinline__ u32 pk2bf(float a, float b) {
  return (u32)f2bf(a) | ((u32)f2bf(b) << 16);
}

static __device__ __forceinline__ void async16(void* lds, const void* g) {
  typedef const __attribute__((address_space(1))) unsigned int* gp_t;
  typedef __attribute__((address_space(3))) unsigned int* lp_t;
  __builtin_amdgcn_global_load_lds((gp_t)g, (lp_t)lds, 16, 0, 0);
}

// ---------------- weight transpose + f32->bf16 cast: out[n][k] = in[k][n] ----
__global__ __launch_bounds__(256) void k_transpose(const float* __restrict__ in,
                                                   u16* __restrict__ out,
                                                   int K, int N) {
  __shared__ float t[32][33];
  const int n0 = blockIdx.x * 32, k0 = blockIdx.y * 32;
  const int tx = threadIdx.x & 31, ty = threadIdx.x >> 5;  // 32 x 8
#pragma unroll
  for (int j = 0; j < 4; j++)
    t[ty + j * 8][tx] = in[(size_t)(k0 + ty + j * 8) * N + n0 + tx];
  __syncthreads();
#pragma unroll
  for (int j = 0; j < 4; j++)
    out[(size_t)(n0 + ty + j * 8) * K + k0 + tx] = f2bf(t[tx][ty + j * 8]);
}

// ---------------- layernorm: f32 in -> bf16 out, one wave per row ----------
__global__ __launch_bounds__(256) void k_layernorm(const float* __restrict__ x,
                                                   const float* __restrict__ g,
                                                   const float* __restrict__ b,
                                                   u16* __restrict__ out) {
  const int row  = blockIdx.x * 4 + (threadIdx.x >> 6);
  const int lane = threadIdx.x & 63;
  const float* xr = x + (size_t)row * DM;
  float4 vb[4];
  float s = 0.f, s2 = 0.f;
#pragma unroll
  for (int j = 0; j < 4; j++) {
    float4 v = *(const float4*)(xr + j * 256 + lane * 4);
    vb[j] = v;
    s  += v.x + v.y + v.z + v.w;
    s2 += v.x * v.x + v.y * v.y + v.z * v.z + v.w * v.w;
  }
#pragma unroll
  for (int off = 1; off < 64; off <<= 1) {
    s  += __shfl_xor(s,  off);
    s2 += __shfl_xor(s2, off);
  }
  const float mu   = s * (1.f / DM);
  const float var  = s2 * (1.f / DM) - mu * mu;
  const float rstd = rsqrtf(var + 1e-5f);
  u16* orow = out + (size_t)row * DM;
#pragma unroll
  for (int j = 0; j < 4; j++) {
    const int col = j * 256 + lane * 4;
    uint2 o;
    o.x = pk2bf((vb[j].x - mu) * rstd * g[col + 0] + b[col + 0],
                (vb[j].y - mu) * rstd * g[col + 1] + b[col + 1]);
    o.y = pk2bf((vb[j].z - mu) * rstd * g[col + 2] + b[col + 2],
                (vb[j].w - mu) * rstd * g[col + 3] + b[col + 3]);
    *(uint2*)(orow + col) = o;
  }
}

// ---------------- GEMM: C[M,N] = A[M,K](bf16) @ BT[N,K](bf16)^T + bias -----
// BM=256, 8 waves (512 thr). NWR waves in M (2 or 4); BN = (8/NWR)*64.
// BK=32, 64B LDS rows, XOR bank swizzle: physical slot = logical ^ ((row>>1)&3)
// (write side via pre-swizzled global source; read side on fragment address).
// QUAD-buffered, depth-3 prefetch, ONE barrier per K-step, counted vmcnt.
// EPI: 1 = f32 out (+res), 2 = bf16 gelu out, 4 = fused QKV
template <int EPI, int NWR>
__global__ __launch_bounds__(512, 2) void k_gemm_bt(const u16* __restrict__ A,
                                                    const u16* __restrict__ BT,
                                                    const float* __restrict__ bias0,
                                                    const float* __restrict__ bias1,
                                                    const float* __restrict__ bias2,
                                                    const float* __restrict__ res,
                                                    void* __restrict__ outp,
                                                    int M, int N, int K) {
  constexpr int NWC    = 8 / NWR;
  constexpr int BN     = NWC * 64;          // 256 or 128
  constexpr int MFRAG  = 256 / NWR / 16;    // 8 or 4
  constexpr int ABYTES = 256 * 32 * 2;      // 16 KB per K-tile
  constexpr int BBYTES = BN * 32 * 2;       // 16 or 8 KB
  constexpr int LA     = ABYTES / (512 * 16);  // 2
  constexpr int LB     = BBYTES / (512 * 16);  // 2 or 1
  constexpr int L      = LA + LB;

  __shared__ char Al[4 * ABYTES];
  __shared__ char Bl[4 * BBYTES];

  const int tid = threadIdx.x, wave = tid >> 6, lane = tid & 63;
  // XCD-aware chunked swizzle (nwg % 8 == 0 for all our launches)
  const int nwg = gridDim.x * gridDim.y;
  const int bid = blockIdx.y * gridDim.x + blockIdx.x;
  const int swz = (bid & 7) * (nwg >> 3) + (bid >> 3);
  const int m0 = (swz / gridDim.x) * 256, n0 = (swz % gridDim.x) * BN;
  const int wr = wave / NWC, wc = wave % NWC;
  const int wm = wr * (256 / NWR), wn = wc * 64;
  const int la = lane & 15, lg = lane >> 4;
  const int psw = (la >> 1) & 3;            // read-side XOR swizzle

  fx4 acc[MFRAG][4];
#pragma unroll
  for (int i = 0; i < MFRAG; i++)
#pragma unroll
    for (int j = 0; j < 4; j++) acc[i][j] = fx4{0.f, 0.f, 0.f, 0.f};

  // staging: thread tid's 16B lands at LDS offset (wave*1024 + lane*16) + j*8192
  // physical (row = off/64, slot = (off%64)/16); load logical slot = slot ^ ((row>>1)&3)
  const int arow = tid >> 2;
  const int aslot = ((tid & 3) ^ ((tid >> 3) & 3)) * 8;
  const u16* gA = A  + (size_t)(m0 + arow) * K + aslot;
  const u16* gB = BT + (size_t)(n0 + arow) * K + aslot;

  auto stageg = [&](int buf, int kt) {
#pragma unroll
    for (int j = 0; j < LA; j++)
      async16(Al + buf * ABYTES + j * 8192 + wave * 1024, gA + (size_t)(j * 128) * K + kt);
#pragma unroll
    for (int j = 0; j < LB; j++)
      async16(Bl + buf * BBYTES + j * 8192 + wave * 1024, gB + (size_t)(j * 128) * K + kt);
  };

  const int nk = K >> 5;
  stageg(0, 0);
  stageg(1, 32);
  stageg(2, 64);

  for (int t = 0; t < nk; ++t) {
    const int rem = nk - 1 - t;
    if (rem >= 2)      { asm volatile("s_waitcnt vmcnt(%0)" :: "n"(2 * L) : "memory"); }
    else if (rem == 1) { asm volatile("s_waitcnt vmcnt(%0)" :: "n"(L)     : "memory"); }
    else               { asm volatile("s_waitcnt vmcnt(0)" ::: "memory"); }
    __builtin_amdgcn_s_barrier();
    asm volatile("" ::: "memory");

    const char* Ab = (const char*)Al + (t & 3) * ABYTES;
    const char* Bb = (const char*)Bl + (t & 3) * BBYTES;
    bfx8 av[MFRAG], bv[4];
#pragma unroll
    for (int mt = 0; mt < MFRAG; mt++)
      av[mt] = *(const bfx8*)(Ab + (wm + mt * 16 + la) * 64 + (lg ^ psw) * 16);
#pragma unroll
    for (int nt = 0; nt < 4; nt++)
      bv[nt] = *(const bfx8*)(Bb + (wn + nt * 16 + la) * 64 + (lg ^ psw) * 16);

    if (t + 3 < nk) stageg((t + 3) & 3, (t + 3) * 32);

    __builtin_amdgcn_s_setprio(1);
#pragma unroll
    for (int mt = 0; mt < MFRAG; mt++)
#pragma unroll
      for (int nt = 0; nt < 4; nt++)
        acc[mt][nt] = __builtin_amdgcn_mfma_f32_16x16x32_bf16(av[mt], bv[nt], acc[mt][nt], 0, 0, 0);
    __builtin_amdgcn_s_setprio(0);
    asm volatile("" ::: "memory");
  }

  if constexpr (EPI == 4) {
    const int reg = n0 >> 10;  // 0=Q, 1=K, 2=V (block-uniform)
    const float* bp = (reg == 0) ? bias0 : (reg == 1) ? bias1 : bias2;
#pragma unroll
    for (int nt = 0; nt < 4; nt++) {
      const int n  = n0 + wn + nt * 16 + la;
      const int nl = n & 1023;
      const float bs = bp[nl];
      if (reg < 2) {
        u16* base = (u16*)outp + (size_t)reg * (8u * 1024 * 1024);
#pragma unroll
        for (int mt = 0; mt < MFRAG; mt++)
#pragma unroll
          for (int vv = 0; vv < 4; vv++) {
            const int m = m0 + wm + mt * 16 + lg * 4 + vv;
            base[(size_t)m * 1024 + nl] = f2bf(acc[mt][nt][vv] + bs);
          }
      } else {
        const int hh = nl >> 6, d = nl & 63;
#pragma unroll
        for (int mt = 0; mt < MFRAG; mt++) {
          const int m = m0 + wm + mt * 16 + lg * 4;
          const int bb = m >> 11, s = m & 2047;
          u16* vp = (u16*)outp + 16u * 1024 * 1024 +
                    (((size_t)bb * NH + hh) * DK + d) * SS + s;
          uint2 o;
          o.x = pk2bf(acc[mt][nt][0] + bs, acc[mt][nt][1] + bs);
          o.y = pk2bf(acc[mt][nt][2] + bs, acc[mt][nt][3] + bs);
          *(uint2*)vp = o;
        }
      }
    }
  } else {
#pragma unroll
    for (int nt = 0; nt < 4; nt++) {
      const int n = n0 + wn + nt * 16 + la;
      const float bs = bias0[n];
#pragma unroll
      for (int mt = 0; mt < MFRAG; mt++) {
#pragma unroll
        for (int vv = 0; vv < 4; vv++) {
          const int m = m0 + wm + mt * 16 + lg * 4 + vv;
          const float val = acc[mt][nt][vv] + bs;
          const size_t idx = (size_t)m * N + n;
          if constexpr (EPI == 1) {
            ((float*)outp)[idx] = res[idx] + val;
          } else {
            const float gl = 0.5f * val * (1.f + erff(val * 0.70710678118f));
            ((u16*)outp)[idx] = f2bf(gl);
          }
        }
      }
    }
  }
}

// ---------------- causal flash attention, swapped-QK^T, split-KV ----------
// grid 1024 x 512 threads = 8 waves = 2 groups of 4. Per block: 128 q-rows.
// Group g processes KV chunks (2i+g)*64; each group has its own double-buffered
// K/V in LDS (64 KB total). End: merge the two online-softmax partials via LDS.
__global__ __launch_bounds__(512, 4) void k_attn(const u16* __restrict__ q,
                                                 const u16* __restrict__ k,
                                                 const u16* __restrict__ vt,
                                                 u16* __restrict__ att) {
  __shared__ char sm[65536];   // [group][ K 2x8KB | V 2x8KB ]; merge scratch aliases
  const int bid = blockIdx.x;
  const int bq = 15 - (bid >> 6);
  const int bh = bid & 63;
  const int b = bh >> 4, h = bh & 15;

  const int tid = threadIdx.x, wave = tid >> 6, lane = tid & 63;
  const int g = wave >> 2, wv4 = wave & 3;
  const int la = lane & 15, lg = lane >> 4;
  const int q0 = bq * 128;

  // Q fragments (B-operand): lane holds Q[q=qt*16+la][d = f*32 + lg*8 + j]
  bfx8 qf[2][2];
#pragma unroll
  for (int qt = 0; qt < 2; qt++) {
    const u16* qp = q + (size_t)(b * SS + q0 + wv4 * 32 + qt * 16 + la) * DM + h * DK + lg * 8;
#pragma unroll
    for (int f = 0; f < 2; f++) qf[qt][f] = *(const bfx8*)(qp + f * 32);
  }

  fx4 acc[2][4];
#pragma unroll
  for (int qt = 0; qt < 2; qt++)
#pragma unroll
    for (int dt = 0; dt < 4; dt++) acc[qt][dt] = fx4{0.f, 0.f, 0.f, 0.f};
  float mold[2] = {-10000.f, -10000.f};   // finite floor (log2 units)
  float lsum[2] = {0.f, 0.f};             // per-lane partial

  // staging (pre-swizzled global source, linear LDS dest)
  const int srow = lane >> 3;                   // 0..7
  const int sslot = (lane & 7) ^ srow;          // 16B slot
  const u16* kg0 = k  + (size_t)(b * SS + wv4 * 16 + srow) * DM + h * DK + sslot * 8;
  const u16* vg0 = vt + (size_t)((b * NH + h) * DK + wv4 * 16 + srow) * SS + sslot * 8;
  char* kbase = sm + g * 32768 + wv4 * 2048;            // + buf*8192
  char* vbase = sm + g * 32768 + 16384 + wv4 * 2048;

  const float c1 = 0.18033688f;  // 0.125 * log2(e)
  const int niter = bq + 1;      // chunks for this group: c = 2*i + g

  auto stage = [&](int buf, int i) {
    const int c0 = (2 * i + g) * 64;
#pragma unroll
    for (int j = 0; j < 2; j++)
      async16(kbase + buf * 8192 + j * 1024, kg0 + (size_t)(c0 + j * 8) * DM);
#pragma unroll
    for (int j = 0; j < 2; j++)
      async16(vbase + buf * 8192 + j * 1024, vg0 + (size_t)(j * 8) * SS + c0);
  };

  stage(0, 0);
  int cur = 0;
  const int sw = la & 7;

  for (int i = 0; i < niter; i++) {
    __syncthreads();                 // buf[cur] staged; prev reads done
    if (i + 1 < niter) stage(cur ^ 1, i + 1);
    const int c0 = (2 * i + g) * 64;
    const bool msk = (i == niter - 1);
    const char* Kb = sm + g * 32768 + cur * 8192;
    const char* Vb = sm + g * 32768 + 16384 + cur * 8192;

    // ---- S^T = K @ Q^T : lane holds S^T[kv=t*16+lg*4+r][q=qt*16+la] ----
    fx4 st[2][4];
    __builtin_amdgcn_s_setprio(1);
#pragma unroll
    for (int t = 0; t < 4; t++) {
      const char* kr = Kb + (size_t)(t * 16 + la) * 128;
      bfx8 kf0 = *(const bfx8*)(kr + ((0 + lg) ^ sw) * 16);
      bfx8 kf1 = *(const bfx8*)(kr + ((4 + lg) ^ sw) * 16);
#pragma unroll
      for (int qt = 0; qt < 2; qt++) {
        fx4 z = fx4{0.f, 0.f, 0.f, 0.f};
        z = __builtin_amdgcn_mfma_f32_16x16x32_bf16(kf0, qf[qt][0], z, 0, 0, 0);
        z = __builtin_amdgcn_mfma_f32_16x16x32_bf16(kf1, qf[qt][1], z, 0, 0, 0);
        st[qt][t] = z;
      }
    }
    __builtin_amdgcn_s_setprio(0);

    if (msk) {
#pragma unroll
      for (int qt = 0; qt < 2; qt++) {
        const int qir = q0 + wv4 * 32 + qt * 16 + la;
#pragma unroll
        for (int t = 0; t < 4; t++)
#pragma unroll
          for (int r = 0; r < 4; r++)
            if (c0 + t * 16 + lg * 4 + r > qir) st[qt][t][r] = -1e9f;
      }
    }

    // ---- softmax: shuffle-free deferred path; per-lane partial lsum ----
    float lmx[2];
#pragma unroll
    for (int qt = 0; qt < 2; qt++) {
      float mx = fmaxf(fmaxf(st[qt][0][0], st[qt][0][1]), fmaxf(st[qt][0][2], st[qt][0][3]));
#pragma unroll
      for (int t = 1; t < 4; t++)
        mx = fmaxf(mx, fmaxf(fmaxf(st[qt][t][0], st[qt][t][1]), fmaxf(st[qt][t][2], st[qt][t][3])));
      lmx[qt] = mx * c1;
    }
    const bool def = (lmx[0] <= mold[0] + 8.f) && (lmx[1] <= mold[1] + 8.f);
    if (!__all(def)) {
#pragma unroll
      for (int qt = 0; qt < 2; qt++) {
        float mx = lmx[qt];
        mx = fmaxf(mx, __shfl_xor(mx, 16));
        mx = fmaxf(mx, __shfl_xor(mx, 32));
        const float mnew  = fmaxf(mold[qt], mx);
        const float scale = exp2f(mold[qt] - mnew);
        mold[qt] = mnew;
        lsum[qt] *= scale;
#pragma unroll
        for (int dt = 0; dt < 4; dt++) {
          acc[qt][dt][0] *= scale; acc[qt][dt][1] *= scale;
          acc[qt][dt][2] *= scale; acc[qt][dt][3] *= scale;
        }
      }
    }
    u32 W[2][4][2];
#pragma unroll
    for (int qt = 0; qt < 2; qt++) {
      float ps = 0.f;
#pragma unroll
      for (int t = 0; t < 4; t++) {
        float p0 = exp2f(fmaf(st[qt][t][0], c1, -mold[qt]));
        float p1 = exp2f(fmaf(st[qt][t][1], c1, -mold[qt]));
        float p2 = exp2f(fmaf(st[qt][t][2], c1, -mold[qt]));
        float p3 = exp2f(fmaf(st[qt][t][3], c1, -mold[qt]));
        ps += (p0 + p1) + (p2 + p3);
        W[qt][t][0] = pk2bf(p0, p1);
        W[qt][t][1] = pk2bf(p2, p3);
      }
      lsum[qt] += ps;
    }

    // ---- PV: O^T += V^T @ P^T (P B-frag rebuilt in-register via shfl) ----
    const int sLo = la + ((lg & 1) << 5);
    const int sHi = sLo + 16;
    const bool tHi = (lg >> 1) & 1;
#pragma unroll
    for (int f = 0; f < 2; f++) {
      bfx8 pf[2];
#pragma unroll
      for (int qt = 0; qt < 2; qt++) {
        const u32 a0 = __shfl(W[qt][2 * f][0], sLo), b0 = __shfl(W[qt][2 * f + 1][0], sLo);
        const u32 a1 = __shfl(W[qt][2 * f][1], sLo), b1 = __shfl(W[qt][2 * f + 1][1], sLo);
        const u32 a2 = __shfl(W[qt][2 * f][0], sHi), b2 = __shfl(W[qt][2 * f + 1][0], sHi);
        const u32 a3 = __shfl(W[qt][2 * f][1], sHi), b3 = __shfl(W[qt][2 * f + 1][1], sHi);
        union { u32 u[4]; bfx8 v; } pu;
        pu.u[0] = tHi ? b0 : a0;
        pu.u[1] = tHi ? b1 : a1;
        pu.u[2] = tHi ? b2 : a2;
        pu.u[3] = tHi ? b3 : a3;
        pf[qt] = pu.v;
      }
      __builtin_amdgcn_s_setprio(1);
#pragma unroll
      for (int dt = 0; dt < 4; dt++) {
        const int row = dt * 16 + la;
        bfx8 vf = *(const bfx8*)(Vb + (size_t)row * 128 + (((f << 2) + lg) ^ sw) * 16);
        acc[0][dt] = __builtin_amdgcn_mfma_f32_16x16x32_bf16(vf, pf[0], acc[0][dt], 0, 0, 0);
        acc[1][dt] = __builtin_amdgcn_mfma_f32_16x16x32_bf16(vf, pf[1], acc[1][dt], 0, 0, 0);
      }
      __builtin_amdgcn_s_setprio(0);
    }
    cur ^= 1;
  }

  // ---- finalize per-group lsum (cross-lane, once) ----
#pragma unroll
  for (int qt = 0; qt < 2; qt++) {
    lsum[qt] += __shfl_xor(lsum[qt], 16);
    lsum[qt] += __shfl_xor(lsum[qt], 32);
  }

  // ---- merge group partials via LDS scratch (KV buffers dead) ----
  __syncthreads();
  const int gi = wv4 * 64 + lane;                  // 0..255 within group
  float* scr = (float*)sm + (size_t)gi * 36;       // 36 KB
  if (g == 1) {
#pragma unroll
    for (int qt = 0; qt < 2; qt++)
#pragma unroll
      for (int dt = 0; dt < 4; dt++)
#pragma unroll
        for (int j = 0; j < 4; j++) scr[qt * 16 + dt * 4 + j] = acc[qt][dt][j];
    scr[32] = mold[0]; scr[33] = mold[1];
    scr[34] = lsum[0]; scr[35] = lsum[1];
  }
  __syncthreads();
  if (g == 0) {
#pragma unroll
    for (int qt = 0; qt < 2; qt++) {
      const float mB = scr[32 + qt], lB = scr[34 + qt];
      const float mN = fmaxf(mold[qt], mB);
      const float sA = exp2f(mold[qt] - mN);
      const float sB = exp2f(mB - mN);
      const float inv = 1.f / (lsum[qt] * sA + lB * sB);
      u16* ob = att + (size_t)(b * SS + q0 + wv4 * 32 + qt * 16 + la) * DM + h * DK + lg * 4;
#pragma unroll
      for (int dt = 0; dt < 4; dt++) {
        float o0 = (acc[qt][dt][0] * sA + scr[qt * 16 + dt * 4 + 0] * sB) * inv;
        float o1 = (acc[qt][dt][1] * sA + scr[qt * 16 + dt * 4 + 1] * sB) * inv;
        float o2 = (acc[qt][dt][2] * sA + scr[qt * 16 + dt * 4 + 2] * sB) * inv;
        float o3 = (acc[qt][dt][3] * sA + scr[qt * 16 + dt * 4 + 3] * sB) * inv;
        uint2 o;
        o.x = pk2bf(o0, o1);
        o.y = pk2bf(o2, o3);
        *(uint2*)(ob + dt * 16) = o;
      }
    }
  }
}

// ---------------------------------------------------------------------------
extern "C" void kernel_launch(void* const* d_in, const int* in_sizes, int n_in,
                              void* d_out, int out_size, void* d_ws, size_t ws_size,
                              hipStream_t stream) {
  const float* x    = (const float*)d_in[0];
  const float* wq   = (const float*)d_in[1];
  const float* bq   = (const float*)d_in[2];
  const float* wk   = (const float*)d_in[3];
  const float* bk   = (const float*)d_in[4];
  const float* wv   = (const float*)d_in[5];
  const float* bv   = (const float*)d_in[6];
  const float* wo   = (const float*)d_in[7];
  const float* bo   = (const float*)d_in[8];
  const float* w1   = (const float*)d_in[9];
  const float* b1   = (const float*)d_in[10];
  const float* w2   = (const float*)d_in[11];
  const float* b2   = (const float*)d_in[12];
  const float* ln1g = (const float*)d_in[13];
  const float* ln1b = (const float*)d_in[14];
  const float* ln2g = (const float*)d_in[15];
  const float* ln2b = (const float*)d_in[16];
  float* out = (float*)d_out;

  char* w = (char*)d_ws;
  const size_t MB = 1024ull * 1024ull;
  u16*   wqkv = (u16*)(w + 0 * MB);   // [3072][1024] bf16 (Q,K,V stacked)
  u16*   wot  = (u16*)(w + 6 * MB);   // [1024][1024]
  u16*   w1t  = (u16*)(w + 8 * MB);   // [4096][1024]
  u16*   w2t  = (u16*)(w + 16 * MB);  // [1024][4096]
  float* x2   = (float*)(w + 24 * MB);// [8192][1024] f32
  u16*   hb   = (u16*)(w + 56 * MB);  // [8192][1024] (h, then h2)
  u16*   qb   = (u16*)(w + 72 * MB);  // [8192][1024]; K at +8M u16, V^T at +16M u16
  u16*   kb   = (u16*)(w + 88 * MB);
  u16*   vtb  = (u16*)(w + 104 * MB); // [4][16][64][2048] V^T per head
  u16*   atb  = (u16*)(w + 120 * MB); // [8192][1024]
  u16*   ffb  = (u16*)(w + 72 * MB);  // [8192][4096] overlays q/k/vt/att

  // 1) weight transposes (f32 -> bf16 W^T); QKV stacked into one [3072][1024]
  k_transpose<<<dim3(32, 32),  256, 0, stream>>>(wq, wqkv,               1024, 1024);
  k_transpose<<<dim3(32, 32),  256, 0, stream>>>(wk, wqkv + 1024 * 1024, 1024, 1024);
  k_transpose<<<dim3(32, 32),  256, 0, stream>>>(wv, wqkv + 2048 * 1024, 1024, 1024);
  k_transpose<<<dim3(32, 32),  256, 0, stream>>>(wo, wot, 1024, 1024);
  k_transpose<<<dim3(128, 32), 256, 0, stream>>>(w1, w1t, 1024, 4096);
  k_transpose<<<dim3(32, 128), 256, 0, stream>>>(w2, w2t, 4096, 1024);

  // 2) LN1: x -> h (bf16)
  k_layernorm<<<MROWS / 4, 256, 0, stream>>>(x, ln1g, ln1b, hb);

  // 3) fused QKV projection (Q,K row-major bf16; V per-head-transposed)
  //    BM=256, BN=128 -> grid 24x32 = 768 blocks (3/CU, even)
  k_gemm_bt<4, 4><<<dim3(24, 32), 512, 0, stream>>>(hb, wqkv, bq, bk, bv, nullptr, qb,
                                                    MROWS, 3 * DM, DM);

  // 4) causal flash attention (swapped QK^T, split-KV, 8 waves)
  k_attn<<<dim3(1024), 512, 0, stream>>>(qb, kb, vtb, atb);

  // 5) O projection + residual (f32 x2): BM=256, BN=128 -> 8x32 = 256 blocks
  k_gemm_bt<1, 4><<<dim3(8, 32), 512, 0, stream>>>(atb, wot, bo, nullptr, nullptr, x, x2,
                                                   MROWS, DM, DM);

  // 6) LN2: x2 -> h2 (bf16, reuse hb)
  k_layernorm<<<MROWS / 4, 256, 0, stream>>>(x2, ln2g, ln2b, hb);

  // 7) FF1 + GELU: BM=256, BN=256 -> 16x32 = 512 blocks (2/CU, even)
  k_gemm_bt<2, 2><<<dim3(16, 32), 512, 0, stream>>>(hb, w1t, b1, nullptr, nullptr, nullptr, ffb,
                                                    MROWS, DFF, DM);

  // 8) FF2 + residual -> d_out (f32): BM=256, BN=128 -> 8x32 = 256 blocks
  k_gemm_bt<1, 4><<<dim3(8, 32), 512, 0, stream>>>(ffb, w2t, b2, nullptr, nullptr, x2, out,
                                                   MROWS, DM, DFF);
}